// Round 10
// baseline (349.258 us; speedup 1.0000x reference)
//
#include <hip/hip_runtime.h>
#include <hip/hip_bf16.h>

typedef __hip_bfloat16 bf16;
typedef __attribute__((ext_vector_type(8))) short short8;
typedef __attribute__((ext_vector_type(4))) short short4v;
typedef __attribute__((ext_vector_type(4))) float floatx4;
typedef __attribute__((ext_vector_type(16))) float floatx16;

#define T_SEQ 4096
#define C_DIM 2048
#define NHEAD 16
#define HSZ   128
#define NGRP  4

#define MFMA_BF16(A,B,C) __builtin_amdgcn_mfma_f32_16x16x32_bf16((A),(B),(C),0,0,0)
#define MFMA32(A,B,C)    __builtin_amdgcn_mfma_f32_32x32x16_bf16((A),(B),(C),0,0,0)

__device__ __forceinline__ void gld_lds16(const bf16* g, bf16* l) {
  __builtin_amdgcn_global_load_lds(
      (__attribute__((address_space(1))) void*)(g),
      (__attribute__((address_space(3))) void*)(l), 16, 0, 0);
}

// pack 2 f32 -> 1 dword of 2 bf16
__device__ __forceinline__ unsigned pkbf(float a, float b) {
  bf16 x = __float2bfloat16(a), y = __float2bfloat16(b);
  unsigned short ux = *(unsigned short*)&x, uy = *(unsigned short*)&y;
  return ((unsigned)uy << 16) | ux;
}

// fp32 -> bf16 cast, 8 elements/thread
__global__ void cvt_kernel(const float* __restrict__ src, bf16* __restrict__ dst, long n)
{
  const long i = ((long)blockIdx.x * blockDim.x + threadIdx.x) * 8;
  if (i >= n) return;
  const float4 a = *(const float4*)(src + i);
  const float4 b = *(const float4*)(src + i + 4);
  bf16 tmp[8];
  tmp[0] = __float2bfloat16(a.x); tmp[1] = __float2bfloat16(a.y);
  tmp[2] = __float2bfloat16(a.z); tmp[3] = __float2bfloat16(a.w);
  tmp[4] = __float2bfloat16(b.x); tmp[5] = __float2bfloat16(b.y);
  tmp[6] = __float2bfloat16(b.z); tmp[7] = __float2bfloat16(b.w);
  *(short8*)(dst + i) = *(const short8*)tmp;
}

// C = A (MxK) * B^T (NxK), bf16 in, fp32 accum.
// qkv_mode==1: N=3072. Q/K slots: RoPE FUSED in epilogue. V slot: V^T via LDS.
// qkv_mode==0: fp32 output to Cf with ld = 2048 (proj GEMM).
__global__ __launch_bounds__(256, 3)
void gemm_bt_kernel(const bf16* __restrict__ A, const bf16* __restrict__ B,
                    float* __restrict__ Cf, bf16* __restrict__ Cq,
                    bf16* __restrict__ Ck, bf16* __restrict__ Cvt,
                    const float* __restrict__ cs, const float* __restrict__ sn,
                    int K, int qkv_mode)
{
  __shared__ alignas(16) bf16 smem[128 * 132];
  bf16* As = smem;
  bf16* Bs = smem + 128 * 64;

  const int t  = threadIdx.x;
  const int w  = t >> 6, l = t & 63;
  const int wr = w >> 1, wc = w & 1;
  const int q4 = l >> 4, ln = l & 15;
  const long bm = (long)blockIdx.y * 128;
  const long bn = (long)blockIdx.x * 128;

  floatx4 acc[4][4] = {};

  const bf16* Ab = A + (bm + t / 8) * (long)K + (t % 8) * 8;
  const bf16* Bb = B + (bn + t / 8) * (long)K + (t % 8) * 8;

  for (int k0 = 0; k0 < K; k0 += 64) {
    __syncthreads();
#pragma unroll
    for (int i = 0; i < 4; ++i) {
      gld_lds16(Ab + (long)i * 32 * K + k0, As + (i * 256 + w * 64) * 8);
      gld_lds16(Bb + (long)i * 32 * K + k0, Bs + (i * 256 + w * 64) * 8);
    }
    __syncthreads();
#pragma unroll
    for (int kk = 0; kk < 64; kk += 32) {
      short8 af[4], bfr[4];
      const int co = kk + q4 * 8;
#pragma unroll
      for (int mi = 0; mi < 4; ++mi)
        af[mi] = *(const short8*)(As + (wr * 64 + mi * 16 + ln) * 64 + co);
#pragma unroll
      for (int ni = 0; ni < 4; ++ni)
        bfr[ni] = *(const short8*)(Bs + (wc * 64 + ni * 16 + ln) * 64 + co);
#pragma unroll
      for (int mi = 0; mi < 4; ++mi)
#pragma unroll
        for (int ni = 0; ni < 4; ++ni)
          acc[mi][ni] = MFMA_BF16(af[mi], bfr[ni], acc[mi][ni]);
    }
  }

  if (!qkv_mode) {
#pragma unroll
    for (int mi = 0; mi < 4; ++mi) {
      const long r0 = bm + wr * 64 + mi * 16 + q4 * 4;
#pragma unroll
      for (int ni = 0; ni < 4; ++ni) {
        const long c = bn + wc * 64 + ni * 16 + ln;
#pragma unroll
        for (int r = 0; r < 4; ++r)
          Cf[(r0 + r) * C_DIM + c] = acc[mi][ni][r];
      }
    }
  } else {
    const int cb = blockIdx.x;
    const int g = cb / 6, slot = cb - g * 6;
    if (slot == 5) {
      // V^T: [d][t] per group, staged through LDS for coalesced stores.
      bf16* dstv = Cvt + (long)g * HSZ * T_SEQ;
#pragma unroll
      for (int pass = 0; pass < 2; ++pass) {
        __syncthreads();
        if (wc == pass) {
#pragma unroll
          for (int mi = 0; mi < 4; ++mi) {
            const int tc = wr * 64 + mi * 16 + q4 * 4;
#pragma unroll
            for (int ni = 0; ni < 4; ++ni) {
              const int dr = ni * 16 + ln;
              short4v pk;
#pragma unroll
              for (int r = 0; r < 4; ++r) {
                bf16 v = __float2bfloat16(acc[mi][ni][r]);
                pk[r] = *(short*)&v;
              }
              *(short4v*)(As + dr * 128 + tc) = pk;
            }
          }
        }
        __syncthreads();
        const int row = t >> 2, ch = (t & 3) * 32;
        bf16* gp = dstv + (long)(pass * 64 + row) * T_SEQ + bm + ch;
#pragma unroll
        for (int jj = 0; jj < 4; ++jj)
          *(short8*)(gp + jj * 8) = *(const short8*)(As + row * 128 + ch + jj * 8);
      }
    } else {
      // Q or K with fused RoPE
      bf16* dst = (slot < 4) ? (Cq + (long)(g * 4 + slot) * T_SEQ * HSZ)
                             : (Ck + (long)g * T_SEQ * HSZ);
      const float qs = (slot < 4) ? (0.08838834764831845f * 1.4426950408889634f) : 1.0f;
      __syncthreads();
      bf16* Ts = smem;   // [128][132]
#pragma unroll
      for (int mi = 0; mi < 4; ++mi) {
        const int tl0 = wr * 64 + mi * 16 + q4 * 4;
#pragma unroll
        for (int ni = 0; ni < 4; ++ni) {
          const int cc = wc * 64 + ni * 16 + ln;
#pragma unroll
          for (int r = 0; r < 4; ++r)
            Ts[(tl0 + r) * 132 + cc] = __float2bfloat16(acc[mi][ni][r]);
        }
      }
      __syncthreads();
      const int tl = t >> 1, d0 = (t & 1) * 32;
      const long trow = bm + tl;
      bf16* gp = dst + trow * HSZ;
#pragma unroll
      for (int dj = 0; dj < 4; ++dj) {
        const int d = d0 + dj * 8;
        const short8 v1 = *(const short8*)(Ts + tl * 132 + d);
        const short8 v2 = *(const short8*)(Ts + tl * 132 + d + 64);
        const float4 c0 = *(const float4*)(cs + trow * 64 + d);
        const float4 c1 = *(const float4*)(cs + trow * 64 + d + 4);
        const float4 s0 = *(const float4*)(sn + trow * 64 + d);
        const float4 s1 = *(const float4*)(sn + trow * 64 + d + 4);
        const float ccv[8] = {c0.x,c0.y,c0.z,c0.w,c1.x,c1.y,c1.z,c1.w};
        const float ssv[8] = {s0.x,s0.y,s0.z,s0.w,s1.x,s1.y,s1.z,s1.w};
        short8 o1, o2;
#pragma unroll
        for (int jj = 0; jj < 8; ++jj) {
          short u1 = v1[jj], u2 = v2[jj];
          const float x1 = __bfloat162float(*(bf16*)&u1);
          const float x2 = __bfloat162float(*(bf16*)&u2);
          bf16 y1 = __float2bfloat16((x1 * ccv[jj] - x2 * ssv[jj]) * qs);
          bf16 y2 = __float2bfloat16((x2 * ccv[jj] + x1 * ssv[jj]) * qs);
          o1[jj] = *(short*)&y1; o2[jj] = *(short*)&y2;
        }
        *(short8*)(gp + d) = o1;
        *(short8*)(gp + d + 64) = o2;
      }
    }
  }
}

// Causal flash attention, GQA 4:1. BQ=128 (4 waves x 32 rows), BKV=64.
// R9's equal-work split-KV shell (grid 512, pair (c,31-c), blocks A/B of 33
// units, partial O/l + combine) with R1's CORRECTNESS-VERIFIED swapped-QK^T
// 32x32 core: S^T = mfma(K, Q) puts each q-row's P lane-local -> softmax
// (exp2, causal mask, row-sum) fully in-register; P->A-frags via cvt_pk +
// one __shfl_xor(,32) pair exchange. Ps LDS buffer and ones-MFMA DELETED
// (-32KB LDS/unit of the 192KB that made the LDS pipe ~74% busy).
// lb(256,2): ~200 regs/wave; do NOT raise (R7/R8 spill lesson).
__global__ __launch_bounds__(256, 2)
void attn_kernel(const bf16* __restrict__ Qg, const bf16* __restrict__ Kg,
                 const bf16* __restrict__ Vtg, bf16* __restrict__ Y,
                 bf16* __restrict__ Opart, float* __restrict__ Lpart)
{
  __shared__ alignas(16) bf16 Ks[64][132];   // K tile [s][d], pad 132
  __shared__ alignas(16) bf16 Vt[128][68];   // V^T tile [d][s], pad 68

  const int id  = blockIdx.x;                // [0, 512)
  const int h   = id >> 5;
  const int r   = id & 31;
  const int c   = r >> 1;                    // pair index [0,16)
  const int isA = r & 1;
  const int g   = h >> 2;

  const int t = threadIdx.x;
  const int w = t >> 6, l = t & 63;
  const int q32 = l & 31, hi = l >> 5;

  const bf16* Qh = Qg + (long)h * T_SEQ * HSZ;
  const bf16* Kh = Kg + (long)g * T_SEQ * HSZ;
  const bf16* Vh = Vtg + (long)g * HSZ * T_SEQ;   // [d][t]

  // staging lane geometry (unchanged from the verified shell)
  const int krow = t >> 4, kc = (t & 15) * 8;
  const int vrow = t >> 3, vc = (t & 7) * 8;

  const int nph = isA ? 2 : 1;
  for (int ph = 0; ph < nph; ++ph) {
    const int P      = (isA && ph == 0) ? c : (31 - c);
    const int jlo    = (isA && ph == 1) ? 33 : 0;
    const int jhi    = isA ? (ph == 0 ? (2 * c + 2) : (64 - 2 * c)) : 33;
    const bool direct = (isA && ph == 0);
    const int qbase  = P * 128 + w * 32;
    const int qrow   = qbase + q32;

    // Q B-frags: lane holds Q[qrow][kd*16 + hi*8 + j] (pre-scaled in GEMM epi)
    short8 qf[8];
#pragma unroll
    for (int kd = 0; kd < 8; ++kd)
      qf[kd] = *(const short8*)(Qh + (long)qrow * HSZ + kd * 16 + hi * 8);

    floatx16 oacc[4] = {};   // O: lane holds 16 q-rows x col (ni*32 + q32)
    float lacc = 0.f;

    short8 kpre[4], vpre[4];
    {
      const int sb = jlo * 64;
#pragma unroll
      for (int i = 0; i < 4; ++i) {
        kpre[i] = *(const short8*)(Kh + (long)(sb + krow + 16 * i) * HSZ + kc);
        vpre[i] = *(const short8*)(Vh + (long)(vrow + 32 * i) * T_SEQ + sb + vc);
      }
    }

    for (int j = jlo; j < jhi; ++j) {
      const int s0 = j * 64;
      // stage prefetched regs -> LDS
#pragma unroll
      for (int i = 0; i < 4; ++i) {
        *(short8*)(&Ks[krow + 16 * i][kc]) = kpre[i];
        *(short8*)(&Vt[vrow + 32 * i][vc]) = vpre[i];
      }
      __syncthreads();
      // issue prefetch of tile j+1 (a full tile of compute slack)
      if (j + 1 < jhi) {
        const int s1 = s0 + 64;
#pragma unroll
        for (int i = 0; i < 4; ++i) {
          kpre[i] = *(const short8*)(Kh + (long)(s1 + krow + 16 * i) * HSZ + kc);
          vpre[i] = *(const short8*)(Vh + (long)(vrow + 32 * i) * T_SEQ + s1 + vc);
        }
      }

      // S^T = K Q^T : lane (q32,hi) gets S[s = si*32+(r&3)+8*(r>>2)+4*hi][qrow]
      floatx16 st[2] = {};
#pragma unroll
      for (int kd = 0; kd < 8; ++kd) {
        const short8 ka0 = *(const short8*)(&Ks[q32][kd * 16 + hi * 8]);
        const short8 ka1 = *(const short8*)(&Ks[32 + q32][kd * 16 + hi * 8]);
        st[0] = MFMA32(ka0, qf[kd], st[0]);
        st[1] = MFMA32(ka1, qf[kd], st[1]);
      }

      const bool domask = (s0 + 63 > qbase);
#pragma unroll
      for (int si = 0; si < 2; ++si) {
        float pe[16];
#pragma unroll
        for (int rr = 0; rr < 16; ++rr) {
          float v = __builtin_amdgcn_exp2f(st[si][rr]);
          if (domask) {
            const int sg = s0 + si * 32 + (rr & 3) + 8 * (rr >> 2) + 4 * hi;
            if (sg > qrow) v = 0.f;
          }
          pe[rr] = v;
          lacc += v;
        }
        // build PV A-frags: lane needs P[qrow][s = ks*16 + hi*8 + j]
#pragma unroll
        for (int k2 = 0; k2 < 2; ++k2) {
          const int ks = si * 2 + k2;
          const int ub = 8 * k2;
          const unsigned pw0 = pkbf(pe[ub + 0], pe[ub + 1]);
          const unsigned pw1 = pkbf(pe[ub + 2], pe[ub + 3]);
          const unsigned pw2 = pkbf(pe[ub + 4], pe[ub + 5]);
          const unsigned pw3 = pkbf(pe[ub + 6], pe[ub + 7]);
          const unsigned sx0 = (unsigned)__shfl_xor((int)(hi ? pw0 : pw2), 32, 64);
          const unsigned sx1 = (unsigned)__shfl_xor((int)(hi ? pw1 : pw3), 32, 64);
          union { unsigned u4[4]; short8 s8; } pa;
          pa.u4[0] = hi ? sx0 : pw0;
          pa.u4[1] = hi ? sx1 : pw1;
          pa.u4[2] = hi ? pw2 : sx0;
          pa.u4[3] = hi ? pw3 : sx1;
#pragma unroll
          for (int ni = 0; ni < 4; ++ni) {
            const short8 vb = *(const short8*)(&Vt[ni * 32 + q32][ks * 16 + hi * 8]);
            oacc[ni] = MFMA32(pa.s8, vb, oacc[ni]);
          }
        }
      }
      __syncthreads();   // all waves done reading Ks/Vt before next staging write
    }

    // combine l halves: lane q32 (both hi) holds denom of row qbase+q32
    const float lt = lacc + __shfl_xor(lacc, 32, 64);

    if (direct) {
#pragma unroll
      for (int rr = 0; rr < 16; ++rr) {
        const int qloc = (rr & 3) + 8 * (rr >> 2) + 4 * hi;
        const float dv = __shfl(lt, qloc, 64);
        const float inv = (dv > 0.f) ? 1.f / dv : 0.f;
        bf16* yp = Y + (long)(qbase + qloc) * C_DIM + h * HSZ + q32;
#pragma unroll
        for (int ni = 0; ni < 4; ++ni)
          yp[ni * 32] = __float2bfloat16(oacc[ni][rr] * inv);
      }
    } else {
      // partial epilogue: unnormalized O (bf16) + l (fp32), additive across halves
      const int sidx = (h * 16 + (15 - c)) * 2 + isA;   // B->even, A-tail->odd
      bf16* Op = Opart + (long)sidx * (128 * 128);
      float* Lp = Lpart + sidx * 128;
      if (hi == 0) Lp[w * 32 + q32] = lt;
#pragma unroll
      for (int rr = 0; rr < 16; ++rr) {
        const int qloc = (rr & 3) + 8 * (rr >> 2) + 4 * hi;
#pragma unroll
        for (int ni = 0; ni < 4; ++ni)
          Op[(w * 32 + qloc) * 128 + ni * 32 + q32] = __float2bfloat16(oacc[ni][rr]);
      }
    }
  }
}

// Combine the two KV-halves of split q-tiles: O = (O0+O1)/(l0+l1), write Y.
__global__ void combine_kernel(const bf16* __restrict__ Opart,
                               const float* __restrict__ Lpart,
                               bf16* __restrict__ Y)
{
  const int b = blockIdx.x;              // b = h*16 + pp, pp = P-16
  const int h = b >> 4, pp = b & 15;
  const bf16* O0 = Opart + (long)b * 2 * 16384;
  const bf16* O1 = O0 + 16384;
  const float* L0 = Lpart + b * 256;
  const float* L1 = L0 + 128;
  const long qb = (long)(pp + 16) * 128;
  const int t = threadIdx.x;
#pragma unroll
  for (int it = 0; it < 8; ++it) {
    const int idx = it * 2048 + t * 8;
    const int row = idx >> 7, d = idx & 127;
    const float lsum = L0[row] + L1[row];
    const float inv = (lsum > 0.f) ? 1.f / lsum : 0.f;
    const short8 a = *(const short8*)(O0 + idx);
    const short8 bb = *(const short8*)(O1 + idx);
    short8 o;
#pragma unroll
    for (int jj = 0; jj < 8; ++jj) {
      short ua = a[jj], ub = bb[jj];
      const float fa = __bfloat162float(*(bf16*)&ua);
      const float fb = __bfloat162float(*(bf16*)&ub);
      bf16 y = __float2bfloat16((fa + fb) * inv);
      o[jj] = *(short*)&y;
    }
    *(short8*)(Y + (qb + row) * C_DIM + h * HSZ + d) = o;
  }
}

extern "C" void kernel_launch(void* const* d_in, const int* in_sizes, int n_in,
                              void* d_out, int out_size, void* d_ws, size_t ws_size,
                              hipStream_t stream)
{
  const float* x  = (const float*)d_in[0];
  const float* cs = (const float*)d_in[1];
  const float* sn = (const float*)d_in[2];
  const float* Wa = (const float*)d_in[3];
  const float* Wp = (const float*)d_in[4];
  float* out = (float*)d_out;

  const long nx  = (long)T_SEQ * C_DIM;
  const long nwa = (long)(NHEAD + 2 * NGRP) * HSZ * C_DIM;
  const long nwp = (long)C_DIM * C_DIM;
  const long nqh = (long)NHEAD * T_SEQ * HSZ;
  const long nkg = (long)NGRP * T_SEQ * HSZ;

  const size_t need = (size_t)(nx + nwa + nqh + 2 * nkg + nqh) * sizeof(bf16);
  if (ws_size < need) return;

  bf16* xb  = (bf16*)d_ws;  // after QKV GEMM: reused as attn O-partials (exact fit)
  bf16* Wab = xb + nx;      // after QKV GEMM: reused as attn l-partials (fp32)
  bf16* Q   = Wab + nwa;    // after attn: reused for Wp bf16 copy
  bf16* K   = Q + nqh;
  bf16* Vt  = K + nkg;      // V^T: [g][d][t]
  bf16* Y   = Vt + nkg;
  bf16* Wpb = Q;            // Q dead after attn; cvt(Wp) runs after attn (stream order)
  bf16* Opart = xb;         // 16*16*2*16384 = 8.39M elems == nx
  float* Lpart = (float*)Wab;  // 65536 floats << nwa

  cvt_kernel<<<(int)(nx  / 8 / 256), 256, 0, stream>>>(x,  xb,  nx);
  cvt_kernel<<<(int)(nwa / 8 / 256), 256, 0, stream>>>(Wa, Wab, nwa);
  gemm_bt_kernel<<<dim3(24, 32), 256, 0, stream>>>(xb, Wab, nullptr, Q, K, Vt, cs, sn, C_DIM, 1);
  attn_kernel<<<512, 256, 0, stream>>>(Q, K, Vt, Y, Opart, Lpart);
  combine_kernel<<<256, 256, 0, stream>>>(Opart, Lpart, Y);
  cvt_kernel<<<(int)(nwp / 8 / 256), 256, 0, stream>>>(Wp, Wpb, nwp);
  gemm_bt_kernel<<<dim3(16, 32), 256, 0, stream>>>(Y, Wpb, out, nullptr, nullptr, nullptr, nullptr, nullptr, C_DIM, 0);
}